// Round 8
// baseline (374.963 us; speedup 1.0000x reference)
//
#include <hip/hip_runtime.h>
#include <hip/hip_bf16.h>

typedef __hip_bfloat16 bf16;
using bfv8 = __attribute__((ext_vector_type(8))) __bf16;
using f4_t = __attribute__((ext_vector_type(4))) float;

#define DEVI static __device__ __forceinline__

DEVI unsigned short f2bu(float f) {
    bf16 h = __float2bfloat16(f);
    return __builtin_bit_cast(unsigned short, h);
}
DEVI ushort4 f4_to_b4(float4 v) {
    ushort4 r;
    r.x = f2bu(v.x); r.y = f2bu(v.y); r.z = f2bu(v.z); r.w = f2bu(v.w);
    return r;
}
DEVI void gl2lds16(const void* g, void* l) {
    __builtin_amdgcn_global_load_lds((const __attribute__((address_space(1))) void*)g,
                                     (__attribute__((address_space(3))) void*)l, 16, 0, 0);
}

// DPP row_ror<N>: rotate within each 16-lane row (VALU only, no DS pipe).
template<int N>
DEVI float row_ror(float x) {
    return __builtin_bit_cast(float,
        __builtin_amdgcn_update_dpp(0, __builtin_bit_cast(int, x), 0x120 | N, 0xF, 0xF, false));
}
DEVI float max16(float x) {
    x = fmaxf(x, row_ror<8>(x));
    x = fmaxf(x, row_ror<4>(x));
    x = fmaxf(x, row_ror<2>(x));
    x = fmaxf(x, row_ror<1>(x));
    return x;
}
DEVI float sum16(float x) {
    x += row_ror<8>(x);
    x += row_ror<4>(x);
    x += row_ror<2>(x);
    x += row_ror<1>(x);
    return x;
}

// ---------------------------------------------------------------------------
// prep_cast: fp32 -> bf16 for x (4M elems) and Wq/Wk/Wv/Wo (1M each).
// ---------------------------------------------------------------------------
__global__ __launch_bounds__(256) void prep_cast(
    const float* __restrict__ x, const float* __restrict__ wq, const float* __restrict__ wk,
    const float* __restrict__ wv, const float* __restrict__ wo,
    bf16* __restrict__ xb, bf16* __restrict__ wqb, bf16* __restrict__ wkb,
    bf16* __restrict__ wvb, bf16* __restrict__ wob)
{
    size_t i = (size_t)blockIdx.x * 256 + threadIdx.x;   // float4 index
    const size_t X4 = 1u << 20, W4 = 1u << 18;
    const float* src; bf16* dst; size_t off;
    if (i < X4)              { src = x;  dst = xb;  off = i; }
    else if (i < X4 + W4)    { src = wq; dst = wqb; off = i - X4; }
    else if (i < X4 + 2*W4)  { src = wk; dst = wkb; off = i - X4 - W4; }
    else if (i < X4 + 3*W4)  { src = wv; dst = wvb; off = i - X4 - 2*W4; }
    else                     { src = wo; dst = wob; off = i - X4 - 3*W4; }
    float4 v = ((const float4*)src)[off];
    ((ushort4*)dst)[off] = f4_to_b4(v);
}

// ---------------------------------------------------------------------------
// prep_blocks: re-base tables by +1 row and block into 64x64 bf16 tiles.
//   pekBlk[b][r][d] = bf16(pek[64b + r + 1][d])          b in [0,16]
//   pevBlk[b][d][j] = bf16(pev[64b + j + 1][d])          b in [0,17] (transposed)
// ---------------------------------------------------------------------------
__global__ __launch_bounds__(256) void prep_blocks(
    const float* __restrict__ pek, const float* __restrict__ pev,
    bf16* __restrict__ pekBlk, bf16* __restrict__ pevBlk)
{
    __shared__ bf16 t[64][72];
    const int b = blockIdx.x;                 // 0..17
    const int r = threadIdx.x >> 2, c0 = (threadIdx.x & 3) * 16;

    if (b < 17) {
        const float* src = pek + (size_t)(64 * b + 1 + r) * 64 + c0;
        bf16* dst = pekBlk + (size_t)b * 4096 + r * 64 + c0;
#pragma unroll
        for (int j = 0; j < 16; j += 4)
            *(ushort4*)(dst + j) = f4_to_b4(*(const float4*)(src + j));
    }
    {   // pev: load rows, transpose through LDS
        const float* src = pev + (size_t)(64 * b + 1 + r) * 64 + c0;
#pragma unroll
        for (int j = 0; j < 16; j++) t[r][c0 + j] = __float2bfloat16(src[j]);
        __syncthreads();
        bf16* dst = pevBlk + (size_t)b * 4096 + r * 64 + c0;   // row d=r, cols j
#pragma unroll
        for (int j = 0; j < 16; j++) dst[j] = t[c0 + j][r];
    }
}

// ---------------------------------------------------------------------------
// transpose_v: Vb [bh][l][d] -> Vtb [bh][d][l], 64x64 LDS tiles.
// ---------------------------------------------------------------------------
__global__ __launch_bounds__(256) void transpose_v(const bf16* __restrict__ Vb, bf16* __restrict__ Vtb)
{
    __shared__ __align__(16) bf16 t[64][72];
    const int bh = blockIdx.y, l0 = blockIdx.x * 64;
    const int r = threadIdx.x >> 2, c0 = (threadIdx.x & 3) * 16;
    const bf16* src = Vb + ((size_t)(bh << 10) + l0 + r) * 64 + c0;
    *(int4*)&t[r][c0]     = *(const int4*)src;
    *(int4*)&t[r][c0 + 8] = *(const int4*)(src + 8);
    __syncthreads();
    int4 o[2]; bf16* ob = (bf16*)o;
#pragma unroll
    for (int j = 0; j < 16; j++) ob[j] = t[c0 + j][r];
    bf16* dst = Vtb + ((size_t)(bh << 6) + r) * 1024 + l0 + c0;
    *(int4*)dst = o[0]; *(int4*)(dst + 8) = o[1];
}

// ---------------------------------------------------------------------------
// NT GEMM v2: C[m][n] = sum_k A[m][k]*B[n][k], A/B bf16. Tile 64x128 (M x N),
// BK=64, 4 waves 2x2 of (32x64). 24KB LDS -> ~4 blocks/CU. K-loop is
// register-prefetch pipelined: next k-tile loaded to VGPRs before compute,
// ds_written after the end-of-compute barrier (vmcnt wait is hidden under
// the compute of the current tile instead of draining at the barrier).
// mode 0: out bf16 scattered to [B,H,L,HD] (z selects W / out third)
// mode 1: out fp32 row-major [M,1024]
// ---------------------------------------------------------------------------
__global__ __launch_bounds__(256) void gemm_bt2(
    const bf16* __restrict__ A,
    const bf16* __restrict__ B0, const bf16* __restrict__ B1, const bf16* __restrict__ B2,
    bf16* __restrict__ outb, float* __restrict__ outf, int K, int mode)
{
    __shared__ __align__(16) bf16 As[64 * 64];
    __shared__ __align__(16) bf16 Bs[128 * 64];

    const int tid  = threadIdx.x;
    const int lane = tid & 63, wave = tid >> 6;
    const int quad = lane >> 4, l16 = lane & 15;
    const int wr = wave >> 1, wc = wave & 1;
    const int m0 = blockIdx.y * 64, n0 = blockIdx.x * 128;
    const int z = blockIdx.z;
    const bf16* Bm = (z == 0) ? B0 : (z == 1) ? B1 : B2;

    f4_t zero = {0.f, 0.f, 0.f, 0.f};
    f4_t acc[2][4];
#pragma unroll
    for (int i = 0; i < 2; i++)
#pragma unroll
        for (int j = 0; j < 4; j++) acc[i][j] = zero;

    const int srow8 = lane >> 3;
    const int scol  = (lane & 7) * 8;
    const bf16* Ag = A  + (size_t)(m0 + 16 * wave + srow8) * K + scol;  // 2 instrs, +8 rows
    const bf16* Bg = Bm + (size_t)(n0 + 32 * wave + srow8) * K + scol;  // 4 instrs, +8 rows

    // ---- prologue: stage k=0 via global_load_lds
#pragma unroll
    for (int i = 0; i < 2; i++)
        gl2lds16(Ag + (size_t)(8 * i) * K, &As[(16 * wave + 8 * i) * 64]);
#pragma unroll
    for (int i = 0; i < 4; i++)
        gl2lds16(Bg + (size_t)(8 * i) * K, &Bs[(32 * wave + 8 * i) * 64]);

    for (int k0 = 0;;) {
        __syncthreads();                         // staged tile visible
        const bool more = (k0 + 64 < K);
        int4 pa[2], pb[4];
        if (more) {                              // prefetch next tile to VGPRs
#pragma unroll
            for (int i = 0; i < 2; i++) pa[i] = *(const int4*)(Ag + (size_t)(8 * i) * K + k0 + 64);
#pragma unroll
            for (int i = 0; i < 4; i++) pb[i] = *(const int4*)(Bg + (size_t)(8 * i) * K + k0 + 64);
        }
#pragma unroll
        for (int ks = 0; ks < 2; ks++) {
            bfv8 af[2], bfr[4];
#pragma unroll
            for (int mt = 0; mt < 2; mt++)
                af[mt] = *(const bfv8*)&As[(wr * 32 + mt * 16 + l16) * 64 + ks * 32 + quad * 8];
#pragma unroll
            for (int nt = 0; nt < 4; nt++)
                bfr[nt] = *(const bfv8*)&Bs[(wc * 64 + nt * 16 + l16) * 64 + ks * 32 + quad * 8];
#pragma unroll
            for (int mt = 0; mt < 2; mt++)
#pragma unroll
                for (int nt = 0; nt < 4; nt++)
                    acc[mt][nt] = __builtin_amdgcn_mfma_f32_16x16x32_bf16(af[mt], bfr[nt], acc[mt][nt], 0, 0, 0);
        }
        if (!more) break;
        __syncthreads();                         // all reads done; safe to overwrite
#pragma unroll
        for (int i = 0; i < 2; i++) *(int4*)&As[(16 * wave + 8 * i) * 64 + lane * 8] = pa[i];
#pragma unroll
        for (int i = 0; i < 4; i++) *(int4*)&Bs[(32 * wave + 8 * i) * 64 + lane * 8] = pb[i];
        k0 += 64;
    }

    if (mode == 0) {
        bf16* ob = outb + (size_t)z * (4 * 16 * 1024 * 64);
#pragma unroll
        for (int mt = 0; mt < 2; mt++)
#pragma unroll
            for (int nt = 0; nt < 4; nt++)
#pragma unroll
                for (int r = 0; r < 4; r++) {
                    int m = m0 + wr * 32 + mt * 16 + quad * 4 + r;
                    int n = n0 + wc * 64 + nt * 16 + l16;
                    int b = m >> 10, l = m & 1023, h = n >> 6, hd = n & 63;
                    ob[((size_t)(b * 16 + h) * 1024 + l) * 64 + hd] = __float2bfloat16(acc[mt][nt][r]);
                }
    } else {
#pragma unroll
        for (int mt = 0; mt < 2; mt++)
#pragma unroll
            for (int nt = 0; nt < 4; nt++)
#pragma unroll
                for (int r = 0; r < 4; r++) {
                    int m = m0 + wr * 32 + mt * 16 + quad * 4 + r;
                    int n = n0 + wc * 64 + nt * 16 + l16;
                    outf[(size_t)m * 1024 + n] = acc[mt][nt][r];
                }
    }
}

// ---------------------------------------------------------------------------
// attn_k v8 = v7 + register-prefetch pipelining. Per tile: issue 8x16B
// global loads for tile kt+1 (K, Vt, next pek block, next pev block) BEFORE
// computing tile kt; after the end-of-compute barrier, ds_write them into
// Ks/Vs and the rings — the vmcnt wait hides under a full tile of compute.
// Ring invariants unchanged: tile kt reads pek blocks {Bb,Bb+1} (2 slots),
// pev {Bb..Bb+2} (3 slots); the write for kt+1 replaces exactly the block
// that kt just finished with. Clamped indices stay in-table on the last iter.
// ---------------------------------------------------------------------------
__global__ __launch_bounds__(256) void attn_k(
    const bf16* __restrict__ Qb, const bf16* __restrict__ Kb, const bf16* __restrict__ Vtb,
    const bf16* __restrict__ pekBlk, const bf16* __restrict__ pevBlk, bf16* __restrict__ Ob)
{
    constexpr int ST = 104;
    __shared__ __align__(16) bf16 Ks[64 * 64];
    __shared__ __align__(16) bf16 Vs[64 * 64];
    __shared__ __align__(16) bf16 pekR[2 * 4096];
    __shared__ __align__(16) bf16 pevR[3 * 4096];
    __shared__ __align__(16) bf16 sU[4][16 * ST];
    __shared__ __align__(16) bf16 sP[4][16 * 72];

    const int tid  = threadIdx.x;
    const int lane = tid & 63, wave = tid >> 6;
    const int quad = lane >> 4, l16 = lane & 15;
    const int bh = blockIdx.x;
    const int g  = 15 - blockIdx.y;               // heavy blocks dispatched first
    const int s  = 4 * g + wave;
    const int nkt = g + 1;

    bf16* myU = sU[wave];
    bf16* myP = sP[wave];

    const int srow8 = lane >> 3;
    const int scg   = (lane & 7) ^ srow8;
    const int x8    = l16 & 7;

    // ---- zero U once
    {
        int* p = (int*)myU;
#pragma unroll
        for (int i = 0; i < 13; i++) p[lane + 64 * i] = 0;
    }

    // ---- Q A-fragments, pre-scaled by 1/8
    bfv8 qf[2];
    {
        const bf16* qp = Qb + ((size_t)bh * 1024 + 16 * s + l16) * 64 + quad * 8;
        qf[0] = *(const bfv8*)qp;
        qf[1] = *(const bfv8*)(qp + 32);
#pragma unroll
        for (int j = 0; j < 8; j++) {
            qf[0][j] = (__bf16)((float)qf[0][j] * 0.125f);
            qf[1][j] = (__bf16)((float)qf[1][j] * 0.125f);
        }
    }

    f4_t zero = {0.f, 0.f, 0.f, 0.f};
    f4_t o_acc[4];
    float m_i[4], l_i[4];
#pragma unroll
    for (int i = 0; i < 4; i++) { o_acc[i] = zero; m_i[i] = -1e30f; l_i[i] = 0.f; }

    const bf16* Kbh = Kb  + (size_t)bh * 1024 * 64;
    const bf16* Vbh = Vtb + (size_t)bh * 64 * 1024;
    const int B0 = 15 - g;                        // window base block at kt=0

    // ---- prologue staging: K/V tile 0, pek blocks {B0,B0+1}, pev {B0..B0+2}
#pragma unroll
    for (int i = 0; i < 2; i++) {
        const int row = 8 * wave + 32 * i + srow8;
        gl2lds16(Kbh + (size_t)row * 64 + scg * 8, &Ks[(8 * wave + 32 * i) * 64]);
        gl2lds16(Vbh + (size_t)row * 1024 + scg * 8, &Vs[(8 * wave + 32 * i) * 64]);
    }
#pragma unroll
    for (int i2 = 0; i2 < 2; i2++) {
        const int slot = (B0 + i2) & 1;
#pragma unroll
        for (int i = 0; i < 2; i++) {
            const int row = 16 * wave + 8 * i + srow8;
            gl2lds16(pekBlk + (size_t)(B0 + i2) * 4096 + row * 64 + scg * 8,
                     &pekR[slot * 4096 + (16 * wave + 8 * i) * 64]);
        }
    }
#pragma unroll
    for (int i2 = 0; i2 < 3; i2++) {
        const int slot = (B0 + i2) % 3;
#pragma unroll
        for (int i = 0; i < 2; i++) {
            const int row = 16 * wave + 8 * i + srow8;
            gl2lds16(pevBlk + (size_t)(B0 + i2) * 4096 + row * 64 + scg * 8,
                     &pevR[slot * 4096 + (16 * wave + 8 * i) * 64]);
        }
    }
    __syncthreads();

    for (int kt = 0; kt < nkt; kt++) {
        const int k0 = kt << 6;
        const int Bb = kt - g + 15;               // window base block, in [0,15]
        const int bm3 = Bb % 3;
        const bool hasNext = (kt + 1 < nkt);
        const int ktn = hasNext ? kt + 1 : kt;    // clamp keeps all addrs in-bounds
        const int k0n = ktn << 6;
        const int bN  = ktn - g + 16;             // <=16
        const int cN  = ktn - g + 17;             // <=17

        // ---- prefetch tile kt+1 into VGPRs (8 x 16B, consumed after barrier)
        int4 pK0, pK1, pV0, pV1, pE0, pE1, pX0, pX1;
        {
            const int rowA = 8 * wave + srow8;
            pK0 = *(const int4*)(Kbh + (size_t)(k0n + rowA) * 64 + scg * 8);
            pK1 = *(const int4*)(Kbh + (size_t)(k0n + rowA + 32) * 64 + scg * 8);
            pV0 = *(const int4*)(Vbh + (size_t)rowA * 1024 + k0n + scg * 8);
            pV1 = *(const int4*)(Vbh + (size_t)(rowA + 32) * 1024 + k0n + scg * 8);
            const int row16 = 16 * wave + srow8;
            pE0 = *(const int4*)(pekBlk + (size_t)bN * 4096 + row16 * 64 + scg * 8);
            pE1 = *(const int4*)(pekBlk + (size_t)bN * 4096 + (row16 + 8) * 64 + scg * 8);
            pX0 = *(const int4*)(pevBlk + (size_t)cN * 4096 + row16 * 64 + scg * 8);
            pX1 = *(const int4*)(pevBlk + (size_t)cN * 4096 + (row16 + 8) * 64 + scg * 8);
        }

        // ---- S1 = Qs K^T (4 frags), T = Qs Pek^T (5 frags) — all LDS
        f4_t s1[4], tt[5];
#pragma unroll
        for (int i = 0; i < 4; i++) s1[i] = zero;
#pragma unroll
        for (int i = 0; i < 5; i++) tt[i] = zero;
#pragma unroll
        for (int ks = 0; ks < 2; ks++) {
#pragma unroll
            for (int nt = 0; nt < 4; nt++) {
                bfv8 kf = *(const bfv8*)&Ks[(nt * 16 + l16) * 64 + ((ks * 4 + quad) ^ x8) * 8];
                s1[nt] = __builtin_amdgcn_mfma_f32_16x16x32_bf16(qf[ks], kf, s1[nt], 0, 0, 0);
            }
#pragma unroll
            for (int nt = 0; nt < 5; nt++) {
                const int off  = 48 - 16 * wave + 16 * nt;
                const int slot = (Bb + (off >> 6)) & 1;
                bfv8 pf = *(const bfv8*)&pekR[slot * 4096 + ((off & 63) + l16) * 64
                                              + ((ks * 4 + quad) ^ x8) * 8];
                tt[nt] = __builtin_amdgcn_mfma_f32_16x16x32_bf16(qf[ks], pf, tt[nt], 0, 0, 0);
            }
        }

        // ---- skew gather: 5 rotations per row + select; causal mask
        float sc[4][4];
#pragma unroll
        for (int r = 0; r < 4; r++) {
            int qq = quad * 4 + r;
            int t  = l16 + 15 - qq;
            int srcl = quad * 16 + (t & 15);
            bool lo = (t < 16);
            float rot[5];
#pragma unroll
            for (int j = 0; j < 5; j++) rot[j] = __shfl(tt[j][r], srcl, 64);
#pragma unroll
            for (int nt = 0; nt < 4; nt++) {
                float s2 = lo ? rot[nt] : rot[nt + 1];
                float v = s1[nt][r] + s2;
                int kk = nt * 16 + l16;
                if (k0 + kk > 16 * s + qq) v = -1e30f;
                sc[nt][r] = v;
            }
        }

        // ---- online softmax (DPP reductions, VALU-only)
        float alpha[4];
#pragma unroll
        for (int r = 0; r < 4; r++) {
            float mt = fmaxf(fmaxf(sc[0][r], sc[1][r]), fmaxf(sc[2][r], sc[3][r]));
            mt = max16(mt);
            float mnew = fmaxf(m_i[r], mt);
            alpha[r] = __expf(m_i[r] - mnew);
            m_i[r] = mnew;
        }
#pragma unroll
        for (int nt = 0; nt < 4; nt++)
#pragma unroll
            for (int r = 0; r < 4; r++)
                sc[nt][r] = __expf(sc[nt][r] - m_i[r]);
#pragma unroll
        for (int r = 0; r < 4; r++) {
            float rs = sum16(sc[0][r] + sc[1][r] + sc[2][r] + sc[3][r]);
            l_i[r] = l_i[r] * alpha[r] + rs;
#pragma unroll
            for (int nt = 0; nt < 4; nt++) o_acc[nt][r] *= alpha[r];
        }

        // ---- scatter P and banded U (wave-private LDS)
#pragma unroll
        for (int nt = 0; nt < 4; nt++)
#pragma unroll
            for (int r = 0; r < 4; r++) {
                int qq = quad * 4 + r;
                int kk = nt * 16 + l16;
                bf16 pb = __float2bfloat16(sc[nt][r]);
                myP[qq * 72 + kk] = pb;
                myU[qq * ST + kk - qq + 15] = pb;
            }

        // ---- O += P V ; O += U Pev — all LDS
#pragma unroll
        for (int ks = 0; ks < 2; ks++) {
            bfv8 pa = *(const bfv8*)&myP[l16 * 72 + ks * 32 + quad * 8];
#pragma unroll
            for (int nt = 0; nt < 4; nt++) {
                bfv8 vf = *(const bfv8*)&Vs[(nt * 16 + l16) * 64 + ((ks * 4 + quad) ^ x8) * 8];
                o_acc[nt] = __builtin_amdgcn_mfma_f32_16x16x32_bf16(pa, vf, o_acc[nt], 0, 0, 0);
            }
        }
#pragma unroll
        for (int ks = 0; ks < 3; ks++) {
            bfv8 ua = *(const bfv8*)&myU[l16 * ST + ks * 32 + quad * 8];
            const int off2 = 48 - 16 * wave + 32 * ks + 8 * quad;
            int slot2 = bm3 + (off2 >> 6);
            if (slot2 >= 3) slot2 -= 3;
            const int chunk = (((off2 & 63) >> 3) ^ x8);
#pragma unroll
            for (int nt = 0; nt < 4; nt++) {
                bfv8 pvf = *(const bfv8*)&pevR[slot2 * 4096 + (nt * 16 + l16) * 64 + chunk * 8];
                o_acc[nt] = __builtin_amdgcn_mfma_f32_16x16x32_bf16(ua, pvf, o_acc[nt], 0, 0, 0);
            }
        }

        __syncthreads();                           // all waves done reading tile kt
        if (hasNext) {                             // commit prefetched tile kt+1
            *(int4*)&Ks[(8 * wave) * 64 + lane * 8]        = pK0;
            *(int4*)&Ks[(8 * wave + 32) * 64 + lane * 8]   = pK1;
            *(int4*)&Vs[(8 * wave) * 64 + lane * 8]        = pV0;
            *(int4*)&Vs[(8 * wave + 32) * 64 + lane * 8]   = pV1;
            const int sK = bN & 1, sV = cN % 3;
            *(int4*)&pekR[sK * 4096 + (16 * wave) * 64 + lane * 8]     = pE0;
            *(int4*)&pekR[sK * 4096 + (16 * wave + 8) * 64 + lane * 8] = pE1;
            *(int4*)&pevR[sV * 4096 + (16 * wave) * 64 + lane * 8]     = pX0;
            *(int4*)&pevR[sV * 4096 + (16 * wave + 8) * 64 + lane * 8] = pX1;
            __syncthreads();
        }
    }

    // ---- epilogue
    const int b = bh >> 4, h = bh & 15;
#pragma unroll
    for (int nt = 0; nt < 4; nt++)
#pragma unroll
        for (int r = 0; r < 4; r++) {
            int q = 16 * s + quad * 4 + r;
            int d = nt * 16 + l16;
            Ob[((size_t)(b * 1024 + q)) * 1024 + h * 64 + d] = __float2bfloat16(o_acc[nt][r] / l_i[r]);
        }
}

// ---------------------------------------------------------------------------
extern "C" void kernel_launch(void* const* d_in, const int* in_sizes, int n_in,
                              void* d_out, int out_size, void* d_ws, size_t ws_size,
                              hipStream_t stream) {
    const float* x   = (const float*)d_in[0];
    const float* Wq  = (const float*)d_in[1];
    const float* Wk  = (const float*)d_in[2];
    const float* Wv  = (const float*)d_in[3];
    const float* Wo  = (const float*)d_in[4];
    const float* pek = (const float*)d_in[5];
    const float* pev = (const float*)d_in[6];

    const size_t MB = 1u << 20;
    char* ws = (char*)d_ws;
    bf16* xb     = (bf16*)(ws + 0);          // 8 MB; dead after QKV gemm -> reused as Ao
    bf16* Wqb    = (bf16*)(ws + 8  * MB);
    bf16* Wkb    = (bf16*)(ws + 10 * MB);
    bf16* Wvb    = (bf16*)(ws + 12 * MB);
    bf16* Wob    = (bf16*)(ws + 14 * MB);
    bf16* Qb     = (bf16*)(ws + 16 * MB);    // Q,K,V contiguous (z-offset in gemm epilogue)
    bf16* Kb     = (bf16*)(ws + 24 * MB);
    bf16* Vb     = (bf16*)(ws + 32 * MB);
    bf16* Vtb    = (bf16*)(ws + 40 * MB);
    bf16* pekBlk = (bf16*)(ws + 48 * MB);            // 17*4096*2 B
    bf16* pevBlk = (bf16*)(ws + 48 * MB + 256*1024); // 18*4096*2 B
    bf16* Ao     = xb;

    prep_cast<<<dim3(8192), 256, 0, stream>>>(x, Wq, Wk, Wv, Wo, xb, Wqb, Wkb, Wvb, Wob);
    prep_blocks<<<dim3(18), 256, 0, stream>>>(pek, pev, pekBlk, pevBlk);
    gemm_bt2<<<dim3(8, 64, 3), 256, 0, stream>>>(xb, Wqb, Wkb, Wvb, Qb, nullptr, 1024, 0);
    transpose_v<<<dim3(16, 64), 256, 0, stream>>>(Vb, Vtb);
    attn_k<<<dim3(64, 16), 256, 0, stream>>>(Qb, Kb, Vtb, pekBlk, pevBlk, Ao);
    gemm_bt2<<<dim3(8, 64, 1), 256, 0, stream>>>(Ao, Wob, nullptr, nullptr, nullptr, (float*)d_out, 1024, 1);
}

// Round 9
// 243.665 us; speedup vs baseline: 1.5388x; 1.5388x over previous
//
#include <hip/hip_runtime.h>
#include <hip/hip_bf16.h>

typedef __hip_bfloat16 bf16;
using bfv8 = __attribute__((ext_vector_type(8))) __bf16;
using f4_t = __attribute__((ext_vector_type(4))) float;

#define DEVI static __device__ __forceinline__

DEVI unsigned short f2bu(float f) {
    bf16 h = __float2bfloat16(f);
    return __builtin_bit_cast(unsigned short, h);
}
DEVI ushort4 f4_to_b4(float4 v) {
    ushort4 r;
    r.x = f2bu(v.x); r.y = f2bu(v.y); r.z = f2bu(v.z); r.w = f2bu(v.w);
    return r;
}
DEVI void gl2lds16(const void* g, void* l) {
    __builtin_amdgcn_global_load_lds((const __attribute__((address_space(1))) void*)g,
                                     (__attribute__((address_space(3))) void*)l, 16, 0, 0);
}

// DPP row_ror<N>: rotate within each 16-lane row (VALU only, no DS pipe).
template<int N>
DEVI float row_ror(float x) {
    return __builtin_bit_cast(float,
        __builtin_amdgcn_update_dpp(0, __builtin_bit_cast(int, x), 0x120 | N, 0xF, 0xF, false));
}
DEVI float max16(float x) {
    x = fmaxf(x, row_ror<8>(x));
    x = fmaxf(x, row_ror<4>(x));
    x = fmaxf(x, row_ror<2>(x));
    x = fmaxf(x, row_ror<1>(x));
    return x;
}
DEVI float sum16(float x) {
    x += row_ror<8>(x);
    x += row_ror<4>(x);
    x += row_ror<2>(x);
    x += row_ror<1>(x);
    return x;
}

// ---------------------------------------------------------------------------
// prep_cast: fp32 -> bf16 for x (4M elems) and Wq/Wk/Wv/Wo (1M each).
// ---------------------------------------------------------------------------
__global__ __launch_bounds__(256) void prep_cast(
    const float* __restrict__ x, const float* __restrict__ wq, const float* __restrict__ wk,
    const float* __restrict__ wv, const float* __restrict__ wo,
    bf16* __restrict__ xb, bf16* __restrict__ wqb, bf16* __restrict__ wkb,
    bf16* __restrict__ wvb, bf16* __restrict__ wob)
{
    size_t i = (size_t)blockIdx.x * 256 + threadIdx.x;   // float4 index
    const size_t X4 = 1u << 20, W4 = 1u << 18;
    const float* src; bf16* dst; size_t off;
    if (i < X4)              { src = x;  dst = xb;  off = i; }
    else if (i < X4 + W4)    { src = wq; dst = wqb; off = i - X4; }
    else if (i < X4 + 2*W4)  { src = wk; dst = wkb; off = i - X4 - W4; }
    else if (i < X4 + 3*W4)  { src = wv; dst = wvb; off = i - X4 - 2*W4; }
    else                     { src = wo; dst = wob; off = i - X4 - 3*W4; }
    float4 v = ((const float4*)src)[off];
    ((ushort4*)dst)[off] = f4_to_b4(v);
}

// ---------------------------------------------------------------------------
// prep_blocks: re-base tables by +1 row and block into 64x64 bf16 tiles.
//   pekBlk[b][r][d] = bf16(pek[64b + r + 1][d])          b in [0,16]
//   pevBlk[b][d][j] = bf16(pev[64b + j + 1][d])          b in [0,17] (transposed)
// ---------------------------------------------------------------------------
__global__ __launch_bounds__(256) void prep_blocks(
    const float* __restrict__ pek, const float* __restrict__ pev,
    bf16* __restrict__ pekBlk, bf16* __restrict__ pevBlk)
{
    __shared__ bf16 t[64][72];
    const int b = blockIdx.x;                 // 0..17
    const int r = threadIdx.x >> 2, c0 = (threadIdx.x & 3) * 16;

    if (b < 17) {
        const float* src = pek + (size_t)(64 * b + 1 + r) * 64 + c0;
        bf16* dst = pekBlk + (size_t)b * 4096 + r * 64 + c0;
#pragma unroll
        for (int j = 0; j < 16; j += 4)
            *(ushort4*)(dst + j) = f4_to_b4(*(const float4*)(src + j));
    }
    {   // pev: load rows, transpose through LDS
        const float* src = pev + (size_t)(64 * b + 1 + r) * 64 + c0;
#pragma unroll
        for (int j = 0; j < 16; j++) t[r][c0 + j] = __float2bfloat16(src[j]);
        __syncthreads();
        bf16* dst = pevBlk + (size_t)b * 4096 + r * 64 + c0;   // row d=r, cols j
#pragma unroll
        for (int j = 0; j < 16; j++) dst[j] = t[c0 + j][r];
    }
}

// ---------------------------------------------------------------------------
// transpose_v: Vb [bh][l][d] -> Vtb [bh][d][l], 64x64 LDS tiles.
// ---------------------------------------------------------------------------
__global__ __launch_bounds__(256) void transpose_v(const bf16* __restrict__ Vb, bf16* __restrict__ Vtb)
{
    __shared__ __align__(16) bf16 t[64][72];
    const int bh = blockIdx.y, l0 = blockIdx.x * 64;
    const int r = threadIdx.x >> 2, c0 = (threadIdx.x & 3) * 16;
    const bf16* src = Vb + ((size_t)(bh << 10) + l0 + r) * 64 + c0;
    *(int4*)&t[r][c0]     = *(const int4*)src;
    *(int4*)&t[r][c0 + 8] = *(const int4*)(src + 8);
    __syncthreads();
    int4 o[2]; bf16* ob = (bf16*)o;
#pragma unroll
    for (int j = 0; j < 16; j++) ob[j] = t[c0 + j][r];
    bf16* dst = Vtb + ((size_t)(bh << 6) + r) * 1024 + l0 + c0;
    *(int4*)dst = o[0]; *(int4*)(dst + 8) = o[1];
}

// ---------------------------------------------------------------------------
// NT GEMM (m97 structure, known-good R7 version): C[m][n] = sum_k A[m][k]*B[n][k].
// 128x128 tile, BK=64, 4 waves 2x2, global_load_lds width=16. NO VGPR
// prefetch (R8 lesson: compiler's default occupancy-targeted VGPR budget
// spills register prefetch -> 347MB scratch writes; keep staging on the
// async gl2lds path instead).
// ---------------------------------------------------------------------------
__global__ __launch_bounds__(256) void gemm_bt2(
    const bf16* __restrict__ A,
    const bf16* __restrict__ B0, const bf16* __restrict__ B1, const bf16* __restrict__ B2,
    bf16* __restrict__ outb, float* __restrict__ outf, int K, int mode)
{
    __shared__ __align__(16) bf16 As[128 * 64];
    __shared__ __align__(16) bf16 Bs[128 * 64];

    const int tid  = threadIdx.x;
    const int lane = tid & 63, wave = tid >> 6;
    const int quad = lane >> 4, l16 = lane & 15;
    const int wr = wave >> 1, wc = wave & 1;
    const int m0 = blockIdx.y * 128, n0 = blockIdx.x * 128;
    const int z = blockIdx.z;
    const bf16* Bm = (z == 0) ? B0 : (z == 1) ? B1 : B2;

    f4_t zero = {0.f, 0.f, 0.f, 0.f};
    f4_t acc[4][4];
#pragma unroll
    for (int i = 0; i < 4; i++)
#pragma unroll
        for (int j = 0; j < 4; j++) acc[i][j] = zero;

    const int srow = 32 * wave + (lane >> 3);
    const int scol = (lane & 7) * 8;
    const bf16* Ag = A  + (size_t)(m0 + srow) * K + scol;
    const bf16* Bg = Bm + (size_t)(n0 + srow) * K + scol;

    for (int k0 = 0; k0 < K; k0 += 64) {
#pragma unroll
        for (int i = 0; i < 4; i++) {
            gl2lds16(Ag + (size_t)(8 * i) * K + k0, &As[(32 * wave + 8 * i) * 64]);
            gl2lds16(Bg + (size_t)(8 * i) * K + k0, &Bs[(32 * wave + 8 * i) * 64]);
        }
        __syncthreads();
#pragma unroll
        for (int ks = 0; ks < 2; ks++) {
            bfv8 af[4], bfr[4];
#pragma unroll
            for (int mt = 0; mt < 4; mt++)
                af[mt] = *(const bfv8*)&As[(wr * 64 + mt * 16 + l16) * 64 + ks * 32 + quad * 8];
#pragma unroll
            for (int nt = 0; nt < 4; nt++)
                bfr[nt] = *(const bfv8*)&Bs[(wc * 64 + nt * 16 + l16) * 64 + ks * 32 + quad * 8];
#pragma unroll
            for (int mt = 0; mt < 4; mt++)
#pragma unroll
                for (int nt = 0; nt < 4; nt++)
                    acc[mt][nt] = __builtin_amdgcn_mfma_f32_16x16x32_bf16(af[mt], bfr[nt], acc[mt][nt], 0, 0, 0);
        }
        __syncthreads();
    }

    if (mode == 0) {
        bf16* ob = outb + (size_t)z * (4 * 16 * 1024 * 64);
#pragma unroll
        for (int mt = 0; mt < 4; mt++)
#pragma unroll
            for (int nt = 0; nt < 4; nt++)
#pragma unroll
                for (int r = 0; r < 4; r++) {
                    int m = m0 + wr * 64 + mt * 16 + quad * 4 + r;
                    int n = n0 + wc * 64 + nt * 16 + l16;
                    int b = m >> 10, l = m & 1023, h = n >> 6, hd = n & 63;
                    ob[((size_t)(b * 16 + h) * 1024 + l) * 64 + hd] = __float2bfloat16(acc[mt][nt][r]);
                }
    } else {
#pragma unroll
        for (int mt = 0; mt < 4; mt++)
#pragma unroll
            for (int nt = 0; nt < 4; nt++)
#pragma unroll
                for (int r = 0; r < 4; r++) {
                    int m = m0 + wr * 64 + mt * 16 + quad * 4 + r;
                    int n = n0 + wc * 64 + nt * 16 + l16;
                    outf[(size_t)m * 1024 + n] = acc[mt][nt][r];
                }
    }
}

// ---------------------------------------------------------------------------
// attn_k v8 (kept from R8 — the win): block = one bh, waves = strips 4g+w,
// LDS rings for pek/pev, K/Vt tiles, register-prefetch pipelining of all
// staging (8x16B per tile, committed after the end-of-compute barrier).
// ---------------------------------------------------------------------------
__global__ __launch_bounds__(256) void attn_k(
    const bf16* __restrict__ Qb, const bf16* __restrict__ Kb, const bf16* __restrict__ Vtb,
    const bf16* __restrict__ pekBlk, const bf16* __restrict__ pevBlk, bf16* __restrict__ Ob)
{
    constexpr int ST = 104;
    __shared__ __align__(16) bf16 Ks[64 * 64];
    __shared__ __align__(16) bf16 Vs[64 * 64];
    __shared__ __align__(16) bf16 pekR[2 * 4096];
    __shared__ __align__(16) bf16 pevR[3 * 4096];
    __shared__ __align__(16) bf16 sU[4][16 * ST];
    __shared__ __align__(16) bf16 sP[4][16 * 72];

    const int tid  = threadIdx.x;
    const int lane = tid & 63, wave = tid >> 6;
    const int quad = lane >> 4, l16 = lane & 15;
    const int bh = blockIdx.x;
    const int g  = 15 - blockIdx.y;               // heavy blocks dispatched first
    const int s  = 4 * g + wave;
    const int nkt = g + 1;

    bf16* myU = sU[wave];
    bf16* myP = sP[wave];

    const int srow8 = lane >> 3;
    const int scg   = (lane & 7) ^ srow8;
    const int x8    = l16 & 7;

    // ---- zero U once
    {
        int* p = (int*)myU;
#pragma unroll
        for (int i = 0; i < 13; i++) p[lane + 64 * i] = 0;
    }

    // ---- Q A-fragments, pre-scaled by 1/8
    bfv8 qf[2];
    {
        const bf16* qp = Qb + ((size_t)bh * 1024 + 16 * s + l16) * 64 + quad * 8;
        qf[0] = *(const bfv8*)qp;
        qf[1] = *(const bfv8*)(qp + 32);
#pragma unroll
        for (int j = 0; j < 8; j++) {
            qf[0][j] = (__bf16)((float)qf[0][j] * 0.125f);
            qf[1][j] = (__bf16)((float)qf[1][j] * 0.125f);
        }
    }

    f4_t zero = {0.f, 0.f, 0.f, 0.f};
    f4_t o_acc[4];
    float m_i[4], l_i[4];
#pragma unroll
    for (int i = 0; i < 4; i++) { o_acc[i] = zero; m_i[i] = -1e30f; l_i[i] = 0.f; }

    const bf16* Kbh = Kb  + (size_t)bh * 1024 * 64;
    const bf16* Vbh = Vtb + (size_t)bh * 64 * 1024;
    const int B0 = 15 - g;                        // window base block at kt=0

    // ---- prologue staging: K/V tile 0, pek blocks {B0,B0+1}, pev {B0..B0+2}
#pragma unroll
    for (int i = 0; i < 2; i++) {
        const int row = 8 * wave + 32 * i + srow8;
        gl2lds16(Kbh + (size_t)row * 64 + scg * 8, &Ks[(8 * wave + 32 * i) * 64]);
        gl2lds16(Vbh + (size_t)row * 1024 + scg * 8, &Vs[(8 * wave + 32 * i) * 64]);
    }
#pragma unroll
    for (int i2 = 0; i2 < 2; i2++) {
        const int slot = (B0 + i2) & 1;
#pragma unroll
        for (int i = 0; i < 2; i++) {
            const int row = 16 * wave + 8 * i + srow8;
            gl2lds16(pekBlk + (size_t)(B0 + i2) * 4096 + row * 64 + scg * 8,
                     &pekR[slot * 4096 + (16 * wave + 8 * i) * 64]);
        }
    }
#pragma unroll
    for (int i2 = 0; i2 < 3; i2++) {
        const int slot = (B0 + i2) % 3;
#pragma unroll
        for (int i = 0; i < 2; i++) {
            const int row = 16 * wave + 8 * i + srow8;
            gl2lds16(pevBlk + (size_t)(B0 + i2) * 4096 + row * 64 + scg * 8,
                     &pevR[slot * 4096 + (16 * wave + 8 * i) * 64]);
        }
    }
    __syncthreads();

    for (int kt = 0; kt < nkt; kt++) {
        const int k0 = kt << 6;
        const int Bb = kt - g + 15;               // window base block, in [0,15]
        const int bm3 = Bb % 3;
        const bool hasNext = (kt + 1 < nkt);
        const int ktn = hasNext ? kt + 1 : kt;    // clamp keeps all addrs in-bounds
        const int k0n = ktn << 6;
        const int bN  = ktn - g + 16;             // <=16
        const int cN  = ktn - g + 17;             // <=17

        // ---- prefetch tile kt+1 into VGPRs (8 x 16B, consumed after barrier)
        int4 pK0, pK1, pV0, pV1, pE0, pE1, pX0, pX1;
        {
            const int rowA = 8 * wave + srow8;
            pK0 = *(const int4*)(Kbh + (size_t)(k0n + rowA) * 64 + scg * 8);
            pK1 = *(const int4*)(Kbh + (size_t)(k0n + rowA + 32) * 64 + scg * 8);
            pV0 = *(const int4*)(Vbh + (size_t)rowA * 1024 + k0n + scg * 8);
            pV1 = *(const int4*)(Vbh + (size_t)(rowA + 32) * 1024 + k0n + scg * 8);
            const int row16 = 16 * wave + srow8;
            pE0 = *(const int4*)(pekBlk + (size_t)bN * 4096 + row16 * 64 + scg * 8);
            pE1 = *(const int4*)(pekBlk + (size_t)bN * 4096 + (row16 + 8) * 64 + scg * 8);
            pX0 = *(const int4*)(pevBlk + (size_t)cN * 4096 + row16 * 64 + scg * 8);
            pX1 = *(const int4*)(pevBlk + (size_t)cN * 4096 + (row16 + 8) * 64 + scg * 8);
        }

        // ---- S1 = Qs K^T (4 frags), T = Qs Pek^T (5 frags) — all LDS
        f4_t s1[4], tt[5];
#pragma unroll
        for (int i = 0; i < 4; i++) s1[i] = zero;
#pragma unroll
        for (int i = 0; i < 5; i++) tt[i] = zero;
#pragma unroll
        for (int ks = 0; ks < 2; ks++) {
#pragma unroll
            for (int nt = 0; nt < 4; nt++) {
                bfv8 kf = *(const bfv8*)&Ks[(nt * 16 + l16) * 64 + ((ks * 4 + quad) ^ x8) * 8];
                s1[nt] = __builtin_amdgcn_mfma_f32_16x16x32_bf16(qf[ks], kf, s1[nt], 0, 0, 0);
            }
#pragma unroll
            for (int nt = 0; nt < 5; nt++) {
                const int off  = 48 - 16 * wave + 16 * nt;
                const int slot = (Bb + (off >> 6)) & 1;
                bfv8 pf = *(const bfv8*)&pekR[slot * 4096 + ((off & 63) + l16) * 64
                                              + ((ks * 4 + quad) ^ x8) * 8];
                tt[nt] = __builtin_amdgcn_mfma_f32_16x16x32_bf16(qf[ks], pf, tt[nt], 0, 0, 0);
            }
        }

        // ---- skew gather: 5 rotations per row + select; causal mask
        float sc[4][4];
#pragma unroll
        for (int r = 0; r < 4; r++) {
            int qq = quad * 4 + r;
            int t  = l16 + 15 - qq;
            int srcl = quad * 16 + (t & 15);
            bool lo = (t < 16);
            float rot[5];
#pragma unroll
            for (int j = 0; j < 5; j++) rot[j] = __shfl(tt[j][r], srcl, 64);
#pragma unroll
            for (int nt = 0; nt < 4; nt++) {
                float s2 = lo ? rot[nt] : rot[nt + 1];
                float v = s1[nt][r] + s2;
                int kk = nt * 16 + l16;
                if (k0 + kk > 16 * s + qq) v = -1e30f;
                sc[nt][r] = v;
            }
        }

        // ---- online softmax (DPP reductions, VALU-only)
        float alpha[4];
#pragma unroll
        for (int r = 0; r < 4; r++) {
            float mt = fmaxf(fmaxf(sc[0][r], sc[1][r]), fmaxf(sc[2][r], sc[3][r]));
            mt = max16(mt);
            float mnew = fmaxf(m_i[r], mt);
            alpha[r] = __expf(m_i[r] - mnew);
            m_i[r] = mnew;
        }
#pragma unroll
        for (int nt = 0; nt < 4; nt++)
#pragma unroll
            for (int r = 0; r < 4; r++)
                sc[nt][r] = __expf(sc[nt][r] - m_i[r]);
#pragma unroll
        for (int r = 0; r < 4; r++) {
            float rs = sum16(sc[0][r] + sc[1][r] + sc[2][r] + sc[3][r]);
            l_i[r] = l_i[r] * alpha[r] + rs;
#pragma unroll
            for (int nt = 0; nt < 4; nt++) o_acc[nt][r] *= alpha[r];
        }

        // ---- scatter P and banded U (wave-private LDS)
#pragma unroll
        for (int nt = 0; nt < 4; nt++)
#pragma unroll
            for (int r = 0; r < 4; r++) {
                int qq = quad * 4 + r;
                int kk = nt * 16 + l16;
                bf16 pb = __float2bfloat16(sc[nt][r]);
                myP[qq * 72 + kk] = pb;
                myU[qq * ST + kk - qq + 15] = pb;
            }

        // ---- O += P V ; O += U Pev — all LDS
#pragma unroll
        for (int ks = 0; ks < 2; ks++) {
            bfv8 pa = *(const bfv8*)&myP[l16 * 72 + ks * 32 + quad * 8];
#pragma unroll
            for (int nt = 0; nt < 4; nt++) {
                bfv8 vf = *(const bfv8*)&Vs[(nt * 16 + l16) * 64 + ((ks * 4 + quad) ^ x8) * 8];
                o_acc[nt] = __builtin_amdgcn_mfma_f32_16x16x32_bf16(pa, vf, o_acc[nt], 0, 0, 0);
            }
        }
#pragma unroll
        for (int ks = 0; ks < 3; ks++) {
            bfv8 ua = *(const bfv8*)&myU[l16 * ST + ks * 32 + quad * 8];
            const int off2 = 48 - 16 * wave + 32 * ks + 8 * quad;
            int slot2 = bm3 + (off2 >> 6);
            if (slot2 >= 3) slot2 -= 3;
            const int chunk = (((off2 & 63) >> 3) ^ x8);
#pragma unroll
            for (int nt = 0; nt < 4; nt++) {
                bfv8 pvf = *(const bfv8*)&pevR[slot2 * 4096 + (nt * 16 + l16) * 64 + chunk * 8];
                o_acc[nt] = __builtin_amdgcn_mfma_f32_16x16x32_bf16(ua, pvf, o_acc[nt], 0, 0, 0);
            }
        }

        __syncthreads();                           // all waves done reading tile kt
        if (hasNext) {                             // commit prefetched tile kt+1
            *(int4*)&Ks[(8 * wave) * 64 + lane * 8]        = pK0;
            *(int4*)&Ks[(8 * wave + 32) * 64 + lane * 8]   = pK1;
            *(int4*)&Vs[(8 * wave) * 64 + lane * 8]        = pV0;
            *(int4*)&Vs[(8 * wave + 32) * 64 + lane * 8]   = pV1;
            const int sK = bN & 1, sV = cN % 3;
            *(int4*)&pekR[sK * 4096 + (16 * wave) * 64 + lane * 8]     = pE0;
            *(int4*)&pekR[sK * 4096 + (16 * wave + 8) * 64 + lane * 8] = pE1;
            *(int4*)&pevR[sV * 4096 + (16 * wave) * 64 + lane * 8]     = pX0;
            *(int4*)&pevR[sV * 4096 + (16 * wave + 8) * 64 + lane * 8] = pX1;
            __syncthreads();
        }
    }

    // ---- epilogue
    const int b = bh >> 4, h = bh & 15;
#pragma unroll
    for (int nt = 0; nt < 4; nt++)
#pragma unroll
        for (int r = 0; r < 4; r++) {
            int q = 16 * s + quad * 4 + r;
            int d = nt * 16 + l16;
            Ob[((size_t)(b * 1024 + q)) * 1024 + h * 64 + d] = __float2bfloat16(o_acc[nt][r] / l_i[r]);
        }
}

// ---------------------------------------------------------------------------
extern "C" void kernel_launch(void* const* d_in, const int* in_sizes, int n_in,
                              void* d_out, int out_size, void* d_ws, size_t ws_size,
                              hipStream_t stream) {
    const float* x   = (const float*)d_in[0];
    const float* Wq  = (const float*)d_in[1];
    const float* Wk  = (const float*)d_in[2];
    const float* Wv  = (const float*)d_in[3];
    const float* Wo  = (const float*)d_in[4];
    const float* pek = (const float*)d_in[5];
    const float* pev = (const float*)d_in[6];

    const size_t MB = 1u << 20;
    char* ws = (char*)d_ws;
    bf16* xb     = (bf16*)(ws + 0);          // 8 MB; dead after QKV gemm -> reused as Ao
    bf16* Wqb    = (bf16*)(ws + 8  * MB);
    bf16* Wkb    = (bf16*)(ws + 10 * MB);
    bf16* Wvb    = (bf16*)(ws + 12 * MB);
    bf16* Wob    = (bf16*)(ws + 14 * MB);
    bf16* Qb     = (bf16*)(ws + 16 * MB);    // Q,K,V contiguous (z-offset in gemm epilogue)
    bf16* Kb     = (bf16*)(ws + 24 * MB);
    bf16* Vb     = (bf16*)(ws + 32 * MB);
    bf16* Vtb    = (bf16*)(ws + 40 * MB);
    bf16* pekBlk = (bf16*)(ws + 48 * MB);            // 17*4096*2 B
    bf16* pevBlk = (bf16*)(ws + 48 * MB + 256*1024); // 18*4096*2 B
    bf16* Ao     = xb;

    prep_cast<<<dim3(8192), 256, 0, stream>>>(x, Wq, Wk, Wv, Wo, xb, Wqb, Wkb, Wvb, Wob);
    prep_blocks<<<dim3(18), 256, 0, stream>>>(pek, pev, pekBlk, pevBlk);
    gemm_bt2<<<dim3(8, 32, 3), 256, 0, stream>>>(xb, Wqb, Wkb, Wvb, Qb, nullptr, 1024, 0);
    transpose_v<<<dim3(16, 64), 256, 0, stream>>>(Vb, Vtb);
    attn_k<<<dim3(64, 16), 256, 0, stream>>>(Qb, Kb, Vtb, pekBlk, pevBlk, Ao);
    gemm_bt2<<<dim3(8, 32, 1), 256, 0, stream>>>(Ao, Wob, nullptr, nullptr, nullptr, (float*)d_out, 1024, 1);
}

// Round 10
// 237.920 us; speedup vs baseline: 1.5760x; 1.0241x over previous
//
#include <hip/hip_runtime.h>
#include <hip/hip_bf16.h>

typedef __hip_bfloat16 bf16;
using bfv8 = __attribute__((ext_vector_type(8))) __bf16;
using f4_t = __attribute__((ext_vector_type(4))) float;

#define DEVI static __device__ __forceinline__

DEVI unsigned short f2bu(float f) {
    bf16 h = __float2bfloat16(f);
    return __builtin_bit_cast(unsigned short, h);
}
DEVI ushort4 f4_to_b4(float4 v) {
    ushort4 r;
    r.x = f2bu(v.x); r.y = f2bu(v.y); r.z = f2bu(v.z); r.w = f2bu(v.w);
    return r;
}
DEVI void gl2lds16(const void* g, void* l) {
    __builtin_amdgcn_global_load_lds((const __attribute__((address_space(1))) void*)g,
                                     (__attribute__((address_space(3))) void*)l, 16, 0, 0);
}

// DPP row_ror<N>: rotate within each 16-lane row (VALU only, no DS pipe).
template<int N>
DEVI float row_ror(float x) {
    return __builtin_bit_cast(float,
        __builtin_amdgcn_update_dpp(0, __builtin_bit_cast(int, x), 0x120 | N, 0xF, 0xF, false));
}
DEVI float max16(float x) {
    x = fmaxf(x, row_ror<8>(x));
    x = fmaxf(x, row_ror<4>(x));
    x = fmaxf(x, row_ror<2>(x));
    x = fmaxf(x, row_ror<1>(x));
    return x;
}
DEVI float sum16(float x) {
    x += row_ror<8>(x);
    x += row_ror<4>(x);
    x += row_ror<2>(x);
    x += row_ror<1>(x);
    return x;
}

// ---------------------------------------------------------------------------
// prep_cast: fp32 -> bf16 for x (4M elems) and Wq/Wk/Wv/Wo (1M each).
// ---------------------------------------------------------------------------
__global__ __launch_bounds__(256) void prep_cast(
    const float* __restrict__ x, const float* __restrict__ wq, const float* __restrict__ wk,
    const float* __restrict__ wv, const float* __restrict__ wo,
    bf16* __restrict__ xb, bf16* __restrict__ wqb, bf16* __restrict__ wkb,
    bf16* __restrict__ wvb, bf16* __restrict__ wob)
{
    size_t i = (size_t)blockIdx.x * 256 + threadIdx.x;   // float4 index
    const size_t X4 = 1u << 20, W4 = 1u << 18;
    const float* src; bf16* dst; size_t off;
    if (i < X4)              { src = x;  dst = xb;  off = i; }
    else if (i < X4 + W4)    { src = wq; dst = wqb; off = i - X4; }
    else if (i < X4 + 2*W4)  { src = wk; dst = wkb; off = i - X4 - W4; }
    else if (i < X4 + 3*W4)  { src = wv; dst = wvb; off = i - X4 - 2*W4; }
    else                     { src = wo; dst = wob; off = i - X4 - 3*W4; }
    float4 v = ((const float4*)src)[off];
    ((ushort4*)dst)[off] = f4_to_b4(v);
}

// ---------------------------------------------------------------------------
// prep_blocks: re-base tables by +1 row and block into 64x64 bf16 tiles.
//   pekBlk[b][r][d] = bf16(pek[64b + r + 1][d])          b in [0,16]
//   pevBlk[b][d][j] = bf16(pev[64b + j + 1][d])          b in [0,17] (transposed)
// ---------------------------------------------------------------------------
__global__ __launch_bounds__(256) void prep_blocks(
    const float* __restrict__ pek, const float* __restrict__ pev,
    bf16* __restrict__ pekBlk, bf16* __restrict__ pevBlk)
{
    __shared__ bf16 t[64][72];
    const int b = blockIdx.x;                 // 0..17
    const int r = threadIdx.x >> 2, c0 = (threadIdx.x & 3) * 16;

    if (b < 17) {
        const float* src = pek + (size_t)(64 * b + 1 + r) * 64 + c0;
        bf16* dst = pekBlk + (size_t)b * 4096 + r * 64 + c0;
#pragma unroll
        for (int j = 0; j < 16; j += 4)
            *(ushort4*)(dst + j) = f4_to_b4(*(const float4*)(src + j));
    }
    {   // pev: load rows, transpose through LDS
        const float* src = pev + (size_t)(64 * b + 1 + r) * 64 + c0;
#pragma unroll
        for (int j = 0; j < 16; j++) t[r][c0 + j] = __float2bfloat16(src[j]);
        __syncthreads();
        bf16* dst = pevBlk + (size_t)b * 4096 + r * 64 + c0;   // row d=r, cols j
#pragma unroll
        for (int j = 0; j < 16; j++) dst[j] = t[c0 + j][r];
    }
}

// ---------------------------------------------------------------------------
// NT GEMM v3: C[m][n] = sum_k A[m][k]*B[n][k], A/B bf16. Tile 64x128 (MxN),
// BK=64, 4 waves 2x2 of 32x64, 24KB LDS -> 6 blocks/CU (QKV grid 1536).
// NO VGPR K-prefetch (R8 lesson: spills). Epilogues are LDS-bounced for
// coalesced dwordx4 stores; z==2 bounces TRANSPOSED and writes V^T directly
// (kills the standalone transpose kernel).
//   mode 0, z<2 : bf16 out scattered to [B,H,L,HD] (Q,K)
//   mode 0, z==2: bf16 out to Vtb [BH][HD][L]
//   mode 1      : fp32 out row-major [M,1024]
// ---------------------------------------------------------------------------
__global__ __launch_bounds__(256, 4) void gemm_bt3(
    const bf16* __restrict__ A,
    const bf16* __restrict__ B0, const bf16* __restrict__ B1, const bf16* __restrict__ B2,
    bf16* __restrict__ outb, bf16* __restrict__ vtb, float* __restrict__ outf,
    int K, int mode)
{
    __shared__ __align__(16) bf16 smem[64 * 64 + 128 * 64];   // 24 KB
    bf16* As = smem;               // 64 x 64
    bf16* Bs = smem + 64 * 64;     // 128 x 64
    bf16* Cb = smem;               // epilogue bounce (reuses whole region)

    const int tid  = threadIdx.x;
    const int lane = tid & 63, wave = tid >> 6;
    const int quad = lane >> 4, l16 = lane & 15;
    const int wr = wave >> 1, wc = wave & 1;
    const int m0 = blockIdx.y * 64, n0 = blockIdx.x * 128;
    const int z = blockIdx.z;
    const bf16* Bm = (z == 0) ? B0 : (z == 1) ? B1 : B2;

    f4_t zero = {0.f, 0.f, 0.f, 0.f};
    f4_t acc[2][4];
#pragma unroll
    for (int i = 0; i < 2; i++)
#pragma unroll
        for (int j = 0; j < 4; j++) acc[i][j] = zero;

    const int srow8 = lane >> 3;
    const int scol  = (lane & 7) * 8;
    const bf16* Ag = A  + (size_t)(m0 + 16 * wave + srow8) * K + scol;
    const bf16* Bg = Bm + (size_t)(n0 + 32 * wave + srow8) * K + scol;

    for (int k0 = 0; k0 < K; k0 += 64) {
#pragma unroll
        for (int i = 0; i < 2; i++)
            gl2lds16(Ag + (size_t)(8 * i) * K + k0, &As[(16 * wave + 8 * i) * 64]);
#pragma unroll
        for (int i = 0; i < 4; i++)
            gl2lds16(Bg + (size_t)(8 * i) * K + k0, &Bs[(32 * wave + 8 * i) * 64]);
        __syncthreads();
#pragma unroll
        for (int ks = 0; ks < 2; ks++) {
            bfv8 af[2], bfr[4];
#pragma unroll
            for (int mt = 0; mt < 2; mt++)
                af[mt] = *(const bfv8*)&As[(wr * 32 + mt * 16 + l16) * 64 + ks * 32 + quad * 8];
#pragma unroll
            for (int nt = 0; nt < 4; nt++)
                bfr[nt] = *(const bfv8*)&Bs[(wc * 64 + nt * 16 + l16) * 64 + ks * 32 + quad * 8];
#pragma unroll
            for (int mt = 0; mt < 2; mt++)
#pragma unroll
                for (int nt = 0; nt < 4; nt++)
                    acc[mt][nt] = __builtin_amdgcn_mfma_f32_16x16x32_bf16(af[mt], bfr[nt], acc[mt][nt], 0, 0, 0);
        }
        __syncthreads();
    }

    if (mode == 1) {       // fp32 row-major, already coalesced dword stores
#pragma unroll
        for (int mt = 0; mt < 2; mt++)
#pragma unroll
            for (int nt = 0; nt < 4; nt++)
#pragma unroll
                for (int r = 0; r < 4; r++) {
                    int m = m0 + wr * 32 + mt * 16 + quad * 4 + r;
                    int n = n0 + wc * 64 + nt * 16 + l16;
                    outf[(size_t)m * 1024 + n] = acc[mt][nt][r];
                }
        return;
    }

    const int b  = m0 >> 10, l0 = m0 & 1023, h0 = n0 >> 6;
    if (z < 2) {
        // bounce [m][n], stride 136 (padded)
#pragma unroll
        for (int mt = 0; mt < 2; mt++)
#pragma unroll
            for (int nt = 0; nt < 4; nt++)
#pragma unroll
                for (int r = 0; r < 4; r++) {
                    int mm = wr * 32 + mt * 16 + quad * 4 + r;
                    int nn = wc * 64 + nt * 16 + l16;
                    Cb[mm * 136 + nn] = __float2bfloat16(acc[mt][nt][r]);
                }
        __syncthreads();
        bf16* ob = outb + (size_t)z * (4 * 16 * 1024 * 64);
        const int ri = tid >> 1, hp = ri >> 6, lrow = ri & 63, c0 = (tid & 1) * 32;
        bf16* dst = ob + ((size_t)((b * 16 + h0 + hp) * 1024) + l0 + lrow) * 64 + c0;
        const bf16* srcl = &Cb[lrow * 136 + hp * 64 + c0];
#pragma unroll
        for (int j = 0; j < 4; j++)
            *(int4*)(dst + 8 * j) = *(const int4*)(srcl + 8 * j);
    } else {
        // bounce transposed [n][m], stride 72 (padded) -> write V^T directly
#pragma unroll
        for (int mt = 0; mt < 2; mt++)
#pragma unroll
            for (int nt = 0; nt < 4; nt++)
#pragma unroll
                for (int r = 0; r < 4; r++) {
                    int mm = wr * 32 + mt * 16 + quad * 4 + r;
                    int nn = wc * 64 + nt * 16 + l16;
                    Cb[nn * 72 + mm] = __float2bfloat16(acc[mt][nt][r]);
                }
        __syncthreads();
        const int ri = tid >> 1, c0 = (tid & 1) * 32;        // ri = n' in [0,128)
        const int n = n0 + ri, h = n >> 6, hd = n & 63;
        bf16* dst = vtb + ((size_t)((b * 16 + h) * 64 + hd)) * 1024 + l0 + c0;
        const bf16* srcl = &Cb[ri * 72 + c0];
#pragma unroll
        for (int j = 0; j < 4; j++)
            *(int4*)(dst + 8 * j) = *(const int4*)(srcl + 8 * j);
    }
}

// ---------------------------------------------------------------------------
// attn_k (R7 version — measured 85.7 us; R9's VGPR-prefetch variant was
// neutral/worse, dropped). Block = one bh, waves = strips 4g+w. Zero
// scattered global loads in the k-loop: K/Vt tiles staged per tile, pek/pev
// windows in LDS ring buffers (2 / 3 x 8KB slots), one new 8KB block of each
// staged per tile via width-16 global_load_lds with XOR swizzle.
// ---------------------------------------------------------------------------
__global__ __launch_bounds__(256) void attn_k(
    const bf16* __restrict__ Qb, const bf16* __restrict__ Kb, const bf16* __restrict__ Vtb,
    const bf16* __restrict__ pekBlk, const bf16* __restrict__ pevBlk, bf16* __restrict__ Ob)
{
    constexpr int ST = 104;
    __shared__ __align__(16) bf16 Ks[64 * 64];
    __shared__ __align__(16) bf16 Vs[64 * 64];
    __shared__ __align__(16) bf16 pekR[2 * 4096];
    __shared__ __align__(16) bf16 pevR[3 * 4096];
    __shared__ __align__(16) bf16 sU[4][16 * ST];
    __shared__ __align__(16) bf16 sP[4][16 * 72];

    const int tid  = threadIdx.x;
    const int lane = tid & 63, wave = tid >> 6;
    const int quad = lane >> 4, l16 = lane & 15;
    const int bh = blockIdx.x;
    const int g  = 15 - blockIdx.y;               // heavy blocks dispatched first
    const int s  = 4 * g + wave;
    const int nkt = g + 1;

    bf16* myU = sU[wave];
    bf16* myP = sP[wave];

    const int srow8 = lane >> 3;
    const int scg   = (lane & 7) ^ srow8;
    const int x8    = l16 & 7;

    // ---- zero U once (band positions tile-invariant)
    {
        int* p = (int*)myU;
#pragma unroll
        for (int i = 0; i < 13; i++) p[lane + 64 * i] = 0;
    }

    // ---- Q A-fragments, pre-scaled by 1/8
    bfv8 qf[2];
    {
        const bf16* qp = Qb + ((size_t)bh * 1024 + 16 * s + l16) * 64 + quad * 8;
        qf[0] = *(const bfv8*)qp;
        qf[1] = *(const bfv8*)(qp + 32);
#pragma unroll
        for (int j = 0; j < 8; j++) {
            qf[0][j] = (__bf16)((float)qf[0][j] * 0.125f);
            qf[1][j] = (__bf16)((float)qf[1][j] * 0.125f);
        }
    }

    f4_t zero = {0.f, 0.f, 0.f, 0.f};
    f4_t o_acc[4];
    float m_i[4], l_i[4];
#pragma unroll
    for (int i = 0; i < 4; i++) { o_acc[i] = zero; m_i[i] = -1e30f; l_i[i] = 0.f; }

    const bf16* Kbh = Kb  + (size_t)bh * 1024 * 64;
    const bf16* Vbh = Vtb + (size_t)bh * 64 * 1024;
    const int B0 = 15 - g;                        // window base block at kt=0

    // ---- prologue staging: K/V tile 0, pek blocks {B0,B0+1}, pev {B0..B0+2}
#pragma unroll
    for (int i = 0; i < 2; i++) {
        const int row = 8 * wave + 32 * i + srow8;
        gl2lds16(Kbh + (size_t)row * 64 + scg * 8, &Ks[(8 * wave + 32 * i) * 64]);
        gl2lds16(Vbh + (size_t)row * 1024 + scg * 8, &Vs[(8 * wave + 32 * i) * 64]);
    }
#pragma unroll
    for (int i2 = 0; i2 < 2; i2++) {
        const int slot = (B0 + i2) & 1;
#pragma unroll
        for (int i = 0; i < 2; i++) {
            const int row = 16 * wave + 8 * i + srow8;
            gl2lds16(pekBlk + (size_t)(B0 + i2) * 4096 + row * 64 + scg * 8,
                     &pekR[slot * 4096 + (16 * wave + 8 * i) * 64]);
        }
    }
#pragma unroll
    for (int i2 = 0; i2 < 3; i2++) {
        const int slot = (B0 + i2) % 3;
#pragma unroll
        for (int i = 0; i < 2; i++) {
            const int row = 16 * wave + 8 * i + srow8;
            gl2lds16(pevBlk + (size_t)(B0 + i2) * 4096 + row * 64 + scg * 8,
                     &pevR[slot * 4096 + (16 * wave + 8 * i) * 64]);
        }
    }

    for (int kt = 0; kt < nkt; kt++) {
        const int k0 = kt << 6;
        const int Bb = kt - g + 15;               // window base block, in [0,15]
        const int bm3 = Bb % 3;

        if (kt > 0) {   // stage this tile's K/V + one new block of each table
#pragma unroll
            for (int i = 0; i < 2; i++) {
                const int row = 8 * wave + 32 * i + srow8;
                gl2lds16(Kbh + (size_t)(k0 + row) * 64 + scg * 8, &Ks[(8 * wave + 32 * i) * 64]);
                gl2lds16(Vbh + (size_t)row * 1024 + k0 + scg * 8, &Vs[(8 * wave + 32 * i) * 64]);
            }
            const int bNew = Bb + 1, cNew = Bb + 2;
            const int slotK = bNew & 1, slotV = cNew % 3;
#pragma unroll
            for (int i = 0; i < 2; i++) {
                const int row = 16 * wave + 8 * i + srow8;
                gl2lds16(pekBlk + (size_t)bNew * 4096 + row * 64 + scg * 8,
                         &pekR[slotK * 4096 + (16 * wave + 8 * i) * 64]);
                gl2lds16(pevBlk + (size_t)cNew * 4096 + row * 64 + scg * 8,
                         &pevR[slotV * 4096 + (16 * wave + 8 * i) * 64]);
            }
        }
        __syncthreads();

        // ---- S1 = Qs K^T (4 frags), T = Qs Pek^T (5 frags) — all LDS
        f4_t s1[4], tt[5];
#pragma unroll
        for (int i = 0; i < 4; i++) s1[i] = zero;
#pragma unroll
        for (int i = 0; i < 5; i++) tt[i] = zero;
#pragma unroll
        for (int ks = 0; ks < 2; ks++) {
#pragma unroll
            for (int nt = 0; nt < 4; nt++) {
                bfv8 kf = *(const bfv8*)&Ks[(nt * 16 + l16) * 64 + ((ks * 4 + quad) ^ x8) * 8];
                s1[nt] = __builtin_amdgcn_mfma_f32_16x16x32_bf16(qf[ks], kf, s1[nt], 0, 0, 0);
            }
#pragma unroll
            for (int nt = 0; nt < 5; nt++) {
                const int off  = 48 - 16 * wave + 16 * nt;
                const int slot = (Bb + (off >> 6)) & 1;
                bfv8 pf = *(const bfv8*)&pekR[slot * 4096 + ((off & 63) + l16) * 64
                                              + ((ks * 4 + quad) ^ x8) * 8];
                tt[nt] = __builtin_amdgcn_mfma_f32_16x16x32_bf16(qf[ks], pf, tt[nt], 0, 0, 0);
            }
        }

        // ---- skew gather: 5 rotations per row + select; causal mask
        float sc[4][4];
#pragma unroll
        for (int r = 0; r < 4; r++) {
            int qq = quad * 4 + r;
            int t  = l16 + 15 - qq;
            int srcl = quad * 16 + (t & 15);
            bool lo = (t < 16);
            float rot[5];
#pragma unroll
            for (int j = 0; j < 5; j++) rot[j] = __shfl(tt[j][r], srcl, 64);
#pragma unroll
            for (int nt = 0; nt < 4; nt++) {
                float s2 = lo ? rot[nt] : rot[nt + 1];
                float v = s1[nt][r] + s2;
                int kk = nt * 16 + l16;
                if (k0 + kk > 16 * s + qq) v = -1e30f;
                sc[nt][r] = v;
            }
        }

        // ---- online softmax (DPP reductions, VALU-only)
        float alpha[4];
#pragma unroll
        for (int r = 0; r < 4; r++) {
            float mt = fmaxf(fmaxf(sc[0][r], sc[1][r]), fmaxf(sc[2][r], sc[3][r]));
            mt = max16(mt);
            float mnew = fmaxf(m_i[r], mt);
            alpha[r] = __expf(m_i[r] - mnew);
            m_i[r] = mnew;
        }
#pragma unroll
        for (int nt = 0; nt < 4; nt++)
#pragma unroll
            for (int r = 0; r < 4; r++)
                sc[nt][r] = __expf(sc[nt][r] - m_i[r]);
#pragma unroll
        for (int r = 0; r < 4; r++) {
            float rs = sum16(sc[0][r] + sc[1][r] + sc[2][r] + sc[3][r]);
            l_i[r] = l_i[r] * alpha[r] + rs;
#pragma unroll
            for (int nt = 0; nt < 4; nt++) o_acc[nt][r] *= alpha[r];
        }

        // ---- scatter P and banded U (wave-private LDS)
#pragma unroll
        for (int nt = 0; nt < 4; nt++)
#pragma unroll
            for (int r = 0; r < 4; r++) {
                int qq = quad * 4 + r;
                int kk = nt * 16 + l16;
                bf16 pb = __float2bfloat16(sc[nt][r]);
                myP[qq * 72 + kk] = pb;
                myU[qq * ST + kk - qq + 15] = pb;
            }

        // ---- O += P V ; O += U Pev — all LDS
#pragma unroll
        for (int ks = 0; ks < 2; ks++) {
            bfv8 pa = *(const bfv8*)&myP[l16 * 72 + ks * 32 + quad * 8];
#pragma unroll
            for (int nt = 0; nt < 4; nt++) {
                bfv8 vf = *(const bfv8*)&Vs[(nt * 16 + l16) * 64 + ((ks * 4 + quad) ^ x8) * 8];
                o_acc[nt] = __builtin_amdgcn_mfma_f32_16x16x32_bf16(pa, vf, o_acc[nt], 0, 0, 0);
            }
        }
#pragma unroll
        for (int ks = 0; ks < 3; ks++) {
            bfv8 ua = *(const bfv8*)&myU[l16 * ST + ks * 32 + quad * 8];
            const int off2 = 48 - 16 * wave + 32 * ks + 8 * quad;
            int slot2 = bm3 + (off2 >> 6);
            if (slot2 >= 3) slot2 -= 3;
            const int chunk = (((off2 & 63) >> 3) ^ x8);
#pragma unroll
            for (int nt = 0; nt < 4; nt++) {
                bfv8 pvf = *(const bfv8*)&pevR[slot2 * 4096 + (nt * 16 + l16) * 64 + chunk * 8];
                o_acc[nt] = __builtin_amdgcn_mfma_f32_16x16x32_bf16(ua, pvf, o_acc[nt], 0, 0, 0);
            }
        }
        __syncthreads();   // all LDS consumed; next iteration may restage
    }

    // ---- epilogue
    const int b = bh >> 4, h = bh & 15;
#pragma unroll
    for (int nt = 0; nt < 4; nt++)
#pragma unroll
        for (int r = 0; r < 4; r++) {
            int q = 16 * s + quad * 4 + r;
            int d = nt * 16 + l16;
            Ob[((size_t)(b * 1024 + q)) * 1024 + h * 64 + d] = __float2bfloat16(o_acc[nt][r] / l_i[r]);
        }
}

// ---------------------------------------------------------------------------
extern "C" void kernel_launch(void* const* d_in, const int* in_sizes, int n_in,
                              void* d_out, int out_size, void* d_ws, size_t ws_size,
                              hipStream_t stream) {
    const float* x   = (const float*)d_in[0];
    const float* Wq  = (const float*)d_in[1];
    const float* Wk  = (const float*)d_in[2];
    const float* Wv  = (const float*)d_in[3];
    const float* Wo  = (const float*)d_in[4];
    const float* pek = (const float*)d_in[5];
    const float* pev = (const float*)d_in[6];

    const size_t MB = 1u << 20;
    char* ws = (char*)d_ws;
    bf16* xb     = (bf16*)(ws + 0);          // 8 MB; dead after QKV gemm -> reused as Ao
    bf16* Wqb    = (bf16*)(ws + 8  * MB);
    bf16* Wkb    = (bf16*)(ws + 10 * MB);
    bf16* Wvb    = (bf16*)(ws + 12 * MB);
    bf16* Wob    = (bf16*)(ws + 14 * MB);
    bf16* Qb     = (bf16*)(ws + 16 * MB);    // Q,K contiguous (z-offset in epilogue)
    bf16* Kb     = (bf16*)(ws + 24 * MB);
    bf16* Vtb    = (bf16*)(ws + 32 * MB);    // V^T written directly by gemm z=2
    bf16* pekBlk = (bf16*)(ws + 48 * MB);            // 17*4096*2 B
    bf16* pevBlk = (bf16*)(ws + 48 * MB + 256*1024); // 18*4096*2 B
    bf16* Ao     = xb;

    prep_cast<<<dim3(8192), 256, 0, stream>>>(x, Wq, Wk, Wv, Wo, xb, Wqb, Wkb, Wvb, Wob);
    prep_blocks<<<dim3(18), 256, 0, stream>>>(pek, pev, pekBlk, pevBlk);
    gemm_bt3<<<dim3(8, 64, 3), 256, 0, stream>>>(xb, Wqb, Wkb, Wvb, Qb, Vtb, nullptr, 1024, 0);
    attn_k<<<dim3(64, 16), 256, 0, stream>>>(Qb, Kb, Vtb, pekBlk, pevBlk, Ao);
    gemm_bt3<<<dim3(8, 64, 1), 256, 0, stream>>>(Ao, Wob, nullptr, nullptr, nullptr, nullptr, (float*)d_out, 1024, 1);
}